// Round 15
// baseline (268.136 us; speedup 1.0000x reference)
//
#include <hip/hip_runtime.h>
#include <hip/hip_fp16.h>
#include <math.h>

#define NB 4
#define GH 64
#define GW 64
#define DM 128
#define MW 256
#define NF 10
#define NPTS 65536
#define ENCD 42
#define MT 128         // points per block: two 64-pt half-tiles A (rows 0-63) and B (64-127)
#define TPB 512
#define LDK 264        // act row stride in f16

typedef _Float16 f16x8 __attribute__((ext_vector_type(8)));
typedef __fp16 h16x2 __attribute__((ext_vector_type(2)));
typedef float f32x4 __attribute__((ext_vector_type(4)));
typedef float f32x16 __attribute__((ext_vector_type(16)));

// d_ws: [0,8192) film fp32 (4x512); [8192,...) packed f16 weights.
// Main layers: 32x32x16 B-frags. unit = (ksg*8 + nt8)*64 + lane, 8 halves.
// ksg: layer0 ks 0..11 (K pad 192), layer1 12..27, layer2 28..43, layer3 44..59.
#define KSU 4096       // halves per K=16 slab (8 ntiles * 64 * 8)
#define KS0 0
#define KS1 12
#define KS2 28
#define KS3 44
#define KS_TOTAL 60
#define NUNIT_MAIN (KS_TOTAL * 8 * 64)    // 30720 units (same total as before)
#define NUNIT_OUT (8 * 64)                // w_out 16x16x32 frags, 8 kt
#define OUT_OFF ((size_t)NUNIT_MAIN * 8)

__device__ __forceinline__ float tanh_fast(float v) {
  const float e = __builtin_amdgcn_exp2f(2.8853900818f * v);
  return 1.0f - 2.0f * __builtin_amdgcn_rcpf(1.0f + e);
}

// Fused prep: blocks [0,122) pack weights; blocks [122,126) compute film.
__global__ void prep_kernel(const float* __restrict__ w0, const float* __restrict__ w1,
                            const float* __restrict__ w2, const float* __restrict__ w3,
                            const float* __restrict__ wo,
                            const float* __restrict__ ctx, const float* __restrict__ wf,
                            const float* __restrict__ bf,
                            _Float16* __restrict__ wp, float* __restrict__ filmout) {
  if (blockIdx.x >= 122) {
    const int b = blockIdx.x - 122;
#pragma unroll
    for (int h = 0; h < 2; ++h) {
      const int j = threadIdx.x + h * 256;
      float acc = bf[j];
      for (int k = 0; k < DM; ++k)
        acc = fmaf(ctx[b * DM + k], wf[k * 512 + j], acc);
      filmout[b * 512 + j] = acc;
    }
    return;
  }
  const int u = blockIdx.x * 256 + threadIdx.x;
  const int lane = u & 63;
  if (u < NUNIT_MAIN) {
    // 32x32x16 B-frag pack (layout verified in R4: passed absmax 0.0039)
    const int v = u >> 6;
    const int nt8 = v & 7;       // n-tile of 32
    const int ksg = v >> 3;      // 0..59
    const float* w; int ksl, K;
    if (ksg < KS1)      { w = w0; ksl = ksg - KS0; K = 170; }
    else if (ksg < KS2) { w = w1; ksl = ksg - KS1; K = 256; }
    else if (ksg < KS3) { w = w2; ksl = ksg - KS2; K = 256; }
    else                { w = w3; ksl = ksg - KS3; K = 256; }
    const int n = nt8 * 32 + (lane & 31);
    const int kbase = ksl * 16 + (lane >> 5) * 8;
    _Float16* dst = wp + (size_t)u * 8;
#pragma unroll
    for (int j = 0; j < 8; ++j) {
      const int k = kbase + j;
      dst[j] = (_Float16)((k < K) ? w[k * MW + n] : 0.0f);
    }
  } else {
    // w_out (256 x 3) -> 16x16x32 B-frag, N padded to 16
    const int kt = (u - NUNIT_MAIN) >> 6;
    const int col = lane & 15;
    const int kbase = kt * 32 + (lane >> 4) * 8;
    _Float16* dst = wp + (size_t)u * 8;
#pragma unroll
    for (int j = 0; j < 8; ++j)
      dst[j] = (_Float16)((col < 3) ? wo[(kbase + j) * 3 + col] : 0.0f);
  }
}

__global__ __launch_bounds__(TPB, 4) void decoder_kernel(
    const float* __restrict__ grid, const float* __restrict__ coords,
    const float* __restrict__ b0, const float* __restrict__ b1,
    const float* __restrict__ b2, const float* __restrict__ b3,
    const float* __restrict__ bo,
    const float* __restrict__ film, const _Float16* __restrict__ wpack,
    float* __restrict__ out) {
  __shared__ _Float16 act[MT * LDK];   // 67584 B; rows 0-63 = tile A, 64-127 = tile B
  __shared__ float4 cco4[MT];          // 2048 B

  const int tid = threadIdx.x;
  const int lane = tid & 63;
  const int wc = tid >> 6;             // wave 0..7: owns cols wc*32..wc*32+31 (DISJOINT)
  const int b = blockIdx.x >> 9;
  const int n0 = (blockIdx.x & 511) * MT;

  // packed-GELU constants
  const __half2 gk1 = __float2half2_rn(-2.3022082f);
  const __half2 gk2 = __float2half2_rn(-0.10294324f);
  const __half2 one2 = __float2half2_rn(1.0f);

  // ---- per-point bilinear setup ----
  if (tid < MT) {
    const float x = coords[(size_t)(n0 + tid) * 2 + 0];
    const float y = coords[(size_t)(n0 + tid) * 2 + 1];
    const float cr = (x + 1.0f) * 0.5f * 63.0f;
    const float cc = (y + 1.0f) * 0.5f * 63.0f;
    const float r0f = floorf(cr), q0f = floorf(cc);
    const int r0 = min(max((int)r0f, 0), GH - 1);
    const int q0 = min(max((int)q0f, 0), GW - 1);
    float4 v;
    v.x = __int_as_float(r0);
    v.y = __int_as_float(q0);
    v.z = cr - r0f;
    v.w = cc - q0f;
    cco4[tid] = v;
  }

  // ---- positional encoding (hw sin/cos, revolutions) + zero-pad 170..191 ----
  {
    const int p = tid & (MT - 1);
    const int j = tid >> 7;
    const float x = coords[(size_t)(n0 + p) * 2 + 0];
    const float y = coords[(size_t)(n0 + p) * 2 + 1];
    _Float16* row = act + p * LDK;
    if (j == 0) { row[0] = (_Float16)x; row[1] = (_Float16)y; }
    if (j == 1) {
      for (int c = ENCD + DM; c < ENCD + DM + 22; ++c) row[c] = (_Float16)0.0f;
    }
    for (int i = j; i < NF; i += 4) {
      const float sc = 0.5f * (float)(1 << i);
      const float rx = x * sc, ry = y * sc;
      const float fx = rx - floorf(rx);
      const float fy = ry - floorf(ry);
      row[2 + 4 * i + 0] = (_Float16)__builtin_amdgcn_sinf(fx);
      row[2 + 4 * i + 1] = (_Float16)__builtin_amdgcn_sinf(fy);
      row[2 + 4 * i + 2] = (_Float16)__builtin_amdgcn_cosf(fx);
      row[2 + 4 * i + 3] = (_Float16)__builtin_amdgcn_cosf(fy);
    }
  }
  __syncthreads();

  // ---- bilinear sampling, 4 channels/iter ----
  {
    const float* gb = grid + (size_t)b * (GH * GW * DM);
#pragma unroll
    for (int it = 0; it < (MT * DM / 4) / TPB; ++it) {
      const int idx = it * TPB + tid;
      const int p = idx >> 5;
      const int c = (idx & 31) * 4;
      const float4 cc4 = cco4[p];
      const int r0 = __float_as_int(cc4.x);
      const int q0 = __float_as_int(cc4.y);
      const float frr = cc4.z, frc = cc4.w;
      const int r1 = min(r0 + 1, GH - 1), q1 = min(q0 + 1, GW - 1);
      const float4 v00 = *(const float4*)(gb + (size_t)(r0 * GW + q0) * DM + c);
      const float4 v01 = *(const float4*)(gb + (size_t)(r0 * GW + q1) * DM + c);
      const float4 v10 = *(const float4*)(gb + (size_t)(r1 * GW + q0) * DM + c);
      const float4 v11 = *(const float4*)(gb + (size_t)(r1 * GW + q1) * DM + c);
      float4 vt, vb, vv;
      vt.x = fmaf(v01.x - v00.x, frc, v00.x);
      vt.y = fmaf(v01.y - v00.y, frc, v00.y);
      vt.z = fmaf(v01.z - v00.z, frc, v00.z);
      vt.w = fmaf(v01.w - v00.w, frc, v00.w);
      vb.x = fmaf(v11.x - v10.x, frc, v10.x);
      vb.y = fmaf(v11.y - v10.y, frc, v10.y);
      vb.z = fmaf(v11.z - v10.z, frc, v10.z);
      vb.w = fmaf(v11.w - v10.w, frc, v10.w);
      vv.x = fmaf(vb.x - vt.x, frr, vt.x);
      vv.y = fmaf(vb.y - vt.y, frr, vt.y);
      vv.z = fmaf(vb.z - vt.z, frr, vt.z);
      vv.w = fmaf(vb.w - vt.w, frr, vt.w);
      const h16x2 lo = __builtin_amdgcn_cvt_pkrtz(vv.x, vv.y);
      const h16x2 hi = __builtin_amdgcn_cvt_pkrtz(vv.z, vv.w);
      *(h16x2*)(act + p * LDK + ENCD + c) = lo;
      *(h16x2*)(act + p * LDK + ENCD + c + 2) = hi;
    }
  }

  // ---- FiLM params: one column per lane (col = wc*32 + (lane&31)) ----
  const int col32 = wc * 32 + (lane & 31);
  const float g1s = film[b * 512 + col32] + 1.0f;
  const float btvs = film[b * 512 + MW + col32];
  __syncthreads();

  f32x16 accA[2], accB[2];   // [m-frag of 32 rows]

  // fragment loaders (32x32x16; layouts verified in R4)
  auto loadB = [&](const _Float16* __restrict__ wl, int ks, f16x8& bfr) {
    bfr = *(const f16x8*)(wl + ((size_t)((ks * 8 + wc) * 64 + lane)) * 8);
  };
  auto loadA = [&](int T, int ks, f16x8 (&afr)[2]) {
    const int kof = ks * 16 + (lane >> 5) * 8;
#pragma unroll
    for (int mt = 0; mt < 2; ++mt)
      afr[mt] = *(const f16x8*)(act + (T * 64 + mt * 32 + (lane & 31)) * LDK + kof);
  };

  // packed-f16 GELU on a pair
  auto gelu_pk = [&](h16x2 pk) -> h16x2 {
    __half2 hv = __builtin_bit_cast(__half2, pk);
    __half2 t = __hmul2(hv, hv);
    __half2 w = __hfma2(gk2, t, gk1);
    __half2 z = __hmul2(hv, w);
    __half2 e = h2exp2(z);
    __half2 s = __hadd2(e, one2);
    __half2 r = h2rcp(s);
    __half2 g = __hmul2(hv, r);
    return __builtin_bit_cast(h16x2, g);
  };

  // epilogue group g (0..7): mt = g>>2, q = g&3; regs r = 4q+rr.
  // C/D 32x32: col=lane&31, row=(r&3)+8*(r>>2)+4*(lane>>5)  [R4-verified]
  auto epi_group = [&](int g, int T, f32x16 (&acc)[2], float cb) {
    const int mt = g >> 2, q = g & 3;
    const int rowb = T * 64 + mt * 32 + 8 * q + 4 * (lane >> 5);
    const float v0 = fmaf(acc[mt][4 * q + 0], g1s, cb);
    const float v1 = fmaf(acc[mt][4 * q + 1], g1s, cb);
    const float v2 = fmaf(acc[mt][4 * q + 2], g1s, cb);
    const float v3 = fmaf(acc[mt][4 * q + 3], g1s, cb);
    const h16x2 gA = gelu_pk(__builtin_amdgcn_cvt_pkrtz(v0, v1));
    const h16x2 gB = gelu_pk(__builtin_amdgcn_cvt_pkrtz(v2, v3));
    act[(rowb + 0) * LDK + col32] = (_Float16)gA.x;
    act[(rowb + 1) * LDK + col32] = (_Float16)gA.y;
    act[(rowb + 2) * LDK + col32] = (_Float16)gB.x;
    act[(rowb + 3) * LDK + col32] = (_Float16)gB.y;
  };

  auto zero = [&](f32x16 (&acc)[2]) {
#pragma unroll
    for (int mt = 0; mt < 2; ++mt)
#pragma unroll
      for (int r = 0; r < 16; ++r) acc[mt][r] = 0.f;
  };

  float cb = 0.f;
  auto set_cb = [&](const float* __restrict__ bl) {
    cb = fmaf(bl[col32], g1s, btvs);
  };

  // Segment: Ks ksteps (12 or 16) of tile Tk into accK, B-frags 2 ahead in a
  // rolling 2-buffer; optionally 8 epilogue groups of tile Te on odd slots.
  auto run_seg = [&](const _Float16* __restrict__ wl, int Ks, int Tk,
                     f32x16 (&accK)[2], bool do_epi, int Te,
                     f32x16 (&accE)[2]) {
    f16x8 bb[2];
    loadB(wl, 0, bb[0]);
    loadB(wl, 1, bb[1]);
#pragma unroll
    for (int s = 0; s < 16; ++s) {
      if (s < Ks) {
        f16x8 afr[2];
        loadA(Tk, s, afr);
        accK[0] = __builtin_amdgcn_mfma_f32_32x32x16_f16(afr[0], bb[s & 1], accK[0], 0, 0, 0);
        accK[1] = __builtin_amdgcn_mfma_f32_32x32x16_f16(afr[1], bb[s & 1], accK[1], 0, 0, 0);
        if (s + 2 < Ks) loadB(wl, s + 2, bb[s & 1]);
      }
      if (do_epi && (s & 1)) epi_group(s >> 1, Te, accE, cb);
    }
  };

  const _Float16* wp0 = wpack + (size_t)KS0 * KSU;
  const _Float16* wp1 = wpack + (size_t)KS1 * KSU;
  const _Float16* wp2 = wpack + (size_t)KS2 * KSU;
  const _Float16* wp3 = wpack + (size_t)KS3 * KSU;

  // seg0: K(A,0)
  zero(accA);
  run_seg(wp0, 12, 0, accA, false, 0, accB);
  __syncthreads();

  // seg1: E(A,0) + K(B,0)
  zero(accB); set_cb(b0);
  run_seg(wp0, 12, 1, accB, true, 0, accA);
  __syncthreads();

  // seg2: E(B,0) + K(A,1)
  zero(accA); set_cb(b0);
  run_seg(wp1, 16, 0, accA, true, 1, accB);
  __syncthreads();

  // seg3: E(A,1) + K(B,1)
  zero(accB); set_cb(b1);
  run_seg(wp1, 16, 1, accB, true, 0, accA);
  __syncthreads();

  // seg4: E(B,1) + K(A,2)
  zero(accA); set_cb(b1);
  run_seg(wp2, 16, 0, accA, true, 1, accB);
  __syncthreads();

  // seg5: E(A,2) + K(B,2)
  zero(accB); set_cb(b2);
  run_seg(wp2, 16, 1, accB, true, 0, accA);
  __syncthreads();

  // seg6: E(B,2) + K(A,3)
  zero(accA); set_cb(b2);
  run_seg(wp3, 16, 0, accA, true, 1, accB);
  __syncthreads();

  // seg7: E(A,3) + K(B,3)
  zero(accB); set_cb(b3);
  run_seg(wp3, 16, 1, accB, true, 0, accA);
  __syncthreads();

  // seg8: E(B,3) [all waves] + Kout(tile A, 16x16x32) [waves 0..3] + store A
  {
    set_cb(b3);
    const _Float16* wob = wpack + OUT_OFF;
    const int arow = lane & 15;
    const int kq = (lane >> 4) * 8;
    f32x4 oacc = (f32x4){0.f, 0.f, 0.f, 0.f};
    const int rb = (wc & 3) * 16 + ((wc < 4) ? 0 : 64);  // wave's 16-row slice
#pragma unroll
    for (int s = 0; s < 8; ++s) {
      if (wc < 4) {
        const f16x8 bfr = *(const f16x8*)(wob + (size_t)(s * 64 + lane) * 8);
        const f16x8 afr = *(const f16x8*)(act + (rb + arow) * LDK + s * 32 + kq);
        oacc = __builtin_amdgcn_mfma_f32_16x16x32_f16(afr, bfr, oacc, 0, 0, 0);
      }
      epi_group(s, 1, accB, cb);
    }
    if (wc < 4) {
      const int col = lane & 15;
      if (col < 3) {
        const float bv = bo[col];
        const int rowb = rb + (lane >> 4) * 4;
#pragma unroll
        for (int r = 0; r < 4; ++r)
          out[((size_t)b * NPTS + n0 + rowb + r) * 3 + col] = tanh_fast(oacc[r] + bv);
      }
    }
    __syncthreads();

    // seg9: Kout(tile B) [waves 4..7] + store B
    if (wc >= 4) {
      f32x4 oacc2 = (f32x4){0.f, 0.f, 0.f, 0.f};
#pragma unroll
      for (int kt = 0; kt < 8; ++kt) {
        const f16x8 bfr = *(const f16x8*)(wob + (size_t)(kt * 64 + lane) * 8);
        const f16x8 afr = *(const f16x8*)(act + (rb + arow) * LDK + kt * 32 + kq);
        oacc2 = __builtin_amdgcn_mfma_f32_16x16x32_f16(afr, bfr, oacc2, 0, 0, 0);
      }
      const int col = lane & 15;
      if (col < 3) {
        const float bv = bo[col];
        const int rowb = rb + (lane >> 4) * 4;
#pragma unroll
        for (int r = 0; r < 4; ++r)
          out[((size_t)b * NPTS + n0 + rowb + r) * 3 + col] = tanh_fast(oacc2[r] + bv);
      }
    }
  }
}

extern "C" void kernel_launch(void* const* d_in, const int* in_sizes, int n_in,
                              void* d_out, int out_size, void* d_ws, size_t ws_size,
                              hipStream_t stream) {
  const float* grid   = (const float*)d_in[0];
  const float* ctx    = (const float*)d_in[1];
  const float* coords = (const float*)d_in[2];
  const float* w0 = (const float*)d_in[3];
  const float* b0 = (const float*)d_in[4];
  const float* w1 = (const float*)d_in[5];
  const float* b1 = (const float*)d_in[6];
  const float* w2 = (const float*)d_in[7];
  const float* b2 = (const float*)d_in[8];
  const float* w3 = (const float*)d_in[9];
  const float* b3 = (const float*)d_in[10];
  const float* wf = (const float*)d_in[11];
  const float* bf = (const float*)d_in[12];
  const float* wo = (const float*)d_in[13];
  const float* bo = (const float*)d_in[14];
  float* out = (float*)d_out;

  float* filmbuf = (float*)d_ws;
  _Float16* wpack = (_Float16*)((char*)d_ws + 8192);

  hipLaunchKernelGGL(prep_kernel, dim3(126), dim3(256), 0, stream,
                     w0, w1, w2, w3, wo, ctx, wf, bf, wpack, filmbuf);
  hipLaunchKernelGGL(decoder_kernel, dim3(NB * (NPTS / MT)), dim3(TPB), 0, stream,
                     grid, coords, b0, b1, b2, b3, bo, filmbuf, wpack, out);
}